// Round 7
// baseline (79.468 us; speedup 1.0000x reference)
//
#include <hip/hip_runtime.h>
#include <math.h>

// Bit-exactness with the numpy fp32 reference: NO fma contraction, true IEEE
// division, identical op order. A 1-ULP difference can flip an edge pixel's
// inside test -> wrong face id -> O(1) absmax error.
#pragma clang fp contract(off)

#define TS 16          // 16x16 pixel tile per 256-thread block

// broadcast lane l's value to all lanes (v_readlane -> SGPR, exact bit copy)
__device__ inline float bcastf(float x, int l) {
    return __int_as_float(__builtin_amdgcn_readlane(__float_as_int(x), l));
}
__device__ inline int bcasti(int x, int l) {
    return __builtin_amdgcn_readlane(x, l);
}

// Single-dispatch fused raster + interpolate.
// Slab-of-64 pipeline: lane ln builds triangle s*64+ln's record in registers
// straight from fidx/uv (no setup kernel, no workspace); bbox-cull ballot ->
// SGPR mask; survivors broadcast via v_readlane in ascending-index order
// (first-hit semantics preserved). Zero LDS, no __syncthreads.
__global__ __launch_bounds__(256)
void tb_bake(const float* __restrict__ attr,
             const float* __restrict__ uv,
             const int*   __restrict__ fidx,
             float*       __restrict__ out,
             int res, int n_used, int tiles_x) {
    const float2* uv2 = (const float2*)uv;

    // ---- tile / pixel mapping ----
    int bx = blockIdx.x % tiles_x;
    int by = blockIdx.x / tiles_x;
    int tx = threadIdx.x & (TS - 1);
    int ty = threadIdx.x >> 4;
    int w = bx * TS + tx;
    int h = by * TS + ty;
    bool live = (w < res) && (h < res);
    int pix = h * res + w;
    // pixel-center UV, same ops as reference: (i + 0.5)/res
    float pxx = ((float)w + 0.5f) / (float)res;
    float pxy = ((float)h + 0.5f) / (float)res;

    int wv = threadIdx.x >> 6;   // wave id 0..3 (owns tile rows wv*4..wv*4+3)
    int ln = threadIdx.x & 63;

    // wave outer rect (pixel centers sit >= 0.5/res inside it -> conservative;
    // cull is a pruning heuristic only, correctness is in the exact sign tests)
    float wx0 = (float)(bx * TS) / (float)res;
    float wx1 = (float)(bx * TS + TS) / (float)res;
    float wy0 = (float)(by * TS + wv * 4) / (float)res;
    float wy1 = (float)(by * TS + wv * 4 + 4) / (float)res;

    int   hit = -1;
    float o0 = 0.0f, o1 = 0.0f, o2 = 0.0f;

    int nslab = n_used >> 6;     // n_used is a multiple of 64

    // ---- preload slab 0 raw data (fidx coalesced, uv gathers L2-resident) ----
    int ci0 = 0, ci1 = 0, ci2 = 0;
    float2 cpa = make_float2(0.f, 0.f), cpb = cpa, cpc = cpa;
    if (nslab > 0) {
        ci0 = fidx[3 * ln + 0];
        ci1 = fidx[3 * ln + 1];
        ci2 = fidx[3 * ln + 2];
        cpa = uv2[ci0];
        cpb = uv2[ci1];
        cpc = uv2[ci2];
    }

    for (int s = 0; s < nslab; ++s) {
        // ---- prefetch slab s+1 raw loads (hidden behind this slab's work) ----
        int ni0 = ci0, ni1 = ci1, ni2 = ci2;
        float2 npa = cpa, npb = cpb, npc = cpc;
        if (s + 1 < nslab) {
            int tn = (s + 1) * 64 + ln;
            ni0 = fidx[3 * tn + 0];
            ni1 = fidx[3 * tn + 1];
            ni2 = fidx[3 * tn + 2];
            npa = uv2[ni0];
            npb = uv2[ni1];
            npc = uv2[ni2];
        }

        // ---- in-register per-triangle setup (same op order as reference) ----
        float ax = cpa.x, ay = cpa.y;
        float v0x = cpb.x - ax, v0y = cpb.y - ay;
        float v1x = cpc.x - ax, v1y = cpc.y - ay;
        float d00 = v0x * v0x + v0y * v0y;
        float d01 = v0x * v1x + v0y * v1y;
        float d11 = v1x * v1x + v1y * v1y;
        float denom = d00 * d11 - d01 * d01;
        float ds = (fabsf(denom) < 1e-12f) ? 0.0f : denom;
        // bbox cull vs wave rect; degenerate (ds==0) never passes
        float mnx = fminf(ax, fminf(cpb.x, cpc.x));
        float mxx = fmaxf(ax, fmaxf(cpb.x, cpc.x));
        float mny = fminf(ay, fminf(cpb.y, cpc.y));
        float mxy = fmaxf(ay, fmaxf(cpb.y, cpc.y));
        bool p = (ds != 0.0f) &&
                 (mxx >= wx0) && (mnx <= wx1) &&
                 (mxy >= wy0) && (mny <= wy1);
        unsigned long long mask = __ballot((int)p);

        // ---- survivor loop: pure VALU readlane broadcasts, no memory ----
        while (mask) {
            int l = (int)__ffsll(mask) - 1;     // ascending index = first-hit order
            mask &= (mask - 1);
            float bax  = bcastf(ax,  l);
            float bay  = bcastf(ay,  l);
            float bv0x = bcastf(v0x, l);
            float bv0y = bcastf(v0y, l);
            float bv1x = bcastf(v1x, l);
            float bv1y = bcastf(v1y, l);
            float bd01 = bcastf(d01, l);
            float bds  = bcastf(ds,  l);        // nonzero for survivors
            float bd11 = bcastf(d11, l);
            float bd00 = bcastf(d00, l);
            // same op order as reference _bary
            float v2x = pxx - bax;
            float v2y = pxy - bay;
            float d20 = v2x * bv0x + v2y * bv0y;   // dot(v2, v0)
            float d21 = v2x * bv1x + v2y * bv1y;   // dot(v2, v1)
            float vn = bd11 * d20 - bd01 * d21;    // d11*d20 - d01*d21
            float wn = bd00 * d21 - bd01 * d20;    // d00*d21 - d01*d20
            float sg = (bds > 0.0f) ? 1.0f : -1.0f;
            // sign-prune the divides: vn/ds >= 0 iff vn*sg >= 0 (exact; the
            // quotient keeps the sign, +/-0 numerators pass both forms)
            if (hit < 0 && vn * sg >= 0.0f && wn * sg >= 0.0f) {
                float v  = vn / bds;                // IEEE divide, exact
                float ww = wn / bds;
                float u  = (1.0f - v) - ww;         // left-assoc like reference
                if (u >= 0.0f) {
                    hit = s * 64 + l;               // first (lowest-index) hit
                    // interpolate NOW: gather latency overlaps remaining scan.
                    // vertex ids broadcast from the owner lane's registers.
                    int j0 = bcasti(ci0, l);
                    int j1 = bcasti(ci1, l);
                    int j2 = bcasti(ci2, l);
                    // einsum order: (u*a0 + v*a1) + w*a2
                    o0 = (u * attr[3 * j0 + 0] + v * attr[3 * j1 + 0]) + ww * attr[3 * j2 + 0];
                    o1 = (u * attr[3 * j0 + 1] + v * attr[3 * j1 + 1]) + ww * attr[3 * j2 + 1];
                    o2 = (u * attr[3 * j0 + 2] + v * attr[3 * j1 + 2]) + ww * attr[3 * j2 + 2];
                }
            }
            // non-live lanes count as done so they never block the wave exit
            if (__all((int)(hit >= 0 || !live))) break;
        }
        if (__all((int)(hit >= 0 || !live))) break;

        // rotate pipeline
        ci0 = ni0; ci1 = ni1; ci2 = ni2;
        cpa = npa; cpb = npb; cpc = npc;
    }

    // ---- store (d_out poisoned 0xAA before every launch -> write zeros on miss)
    if (live) {
        out[3 * pix + 0] = o0;
        out[3 * pix + 1] = o1;
        out[3 * pix + 2] = o2;
    }
}

extern "C" void kernel_launch(void* const* d_in, const int* in_sizes, int n_in,
                              void* d_out, int out_size, void* d_ws, size_t ws_size,
                              hipStream_t stream) {
    const float* attr = (const float*)d_in[0];
    const float* uv   = (const float*)d_in[1];
    const int*   fidx = (const int*)d_in[2];
    float*       out  = (float*)d_out;

    int res = (int)lround(sqrt((double)(out_size / 3)));
    int nf = in_sizes[2] / 3;
    int n_used = (nf / 64) * 64;   // reference drops the tail chunk (_CHUNK=64)

    int tiles_x = (res + TS - 1) / TS;
    int nblocks = tiles_x * tiles_x;
    tb_bake<<<nblocks, 256, 0, stream>>>(attr, uv, fidx, out, res, n_used, tiles_x);
}